// Round 2
// baseline (115.043 us; speedup 1.0000x reference)
//
#include <hip/hip_runtime.h>

typedef float f4 __attribute__((ext_vector_type(4)));

#define PAD 68   // 64x64 LDS matrix row stride: 272 B, 16B-aligned

// Chebyshev deg-2 minimax seed for 1/lambda on [2.55, 4.40]:
// X0 = C2*M^2 + C1*M + C0*I ; residual ~5.0e-3, after 1 Newton ~2.5e-5
#define SEED_C2 0.0251681f
#define SEED_C1 (-0.262380f)
#define SEED_C0 0.895613f

// 8x4 output tile per thread, 128 threads cover 64x64.
// acc[m*4+c] = sum_n L[i0+m][n] * R[n][j0+c]   (row stride PAD)
// 12 f4 LDS reads per 128 FMAs (vs 8 per 64 for 4x4) -> 25% less LDS traffic.
__device__ __forceinline__ void mm_acc8x4(const float* L, const float* R,
                                          int i0, int j0, float acc[32]) {
  #pragma unroll
  for (int m = 0; m < 32; ++m) acc[m] = 0.f;
  #pragma unroll
  for (int n = 0; n < 64; n += 4) {
    f4 La[8], Rb[4];
    #pragma unroll
    for (int m = 0; m < 8; ++m) La[m] = *(const f4*)&L[(i0 + m) * PAD + n];
    #pragma unroll
    for (int p = 0; p < 4; ++p) Rb[p] = *(const f4*)&R[(n + p) * PAD + j0];
    #pragma unroll
    for (int m = 0; m < 8; ++m)
      #pragma unroll
      for (int p = 0; p < 4; ++p)
        #pragma unroll
        for (int c = 0; c < 4; ++c)
          acc[m * 4 + c] += La[m][p] * Rb[p][c];
  }
}

// One block per channel d. K[k] = Cv . A_bar^k . B_bar, k=0..31, via
// Cheb-seeded Newton inverse; then A^2-chain with parity split:
//   K[2i]   = Cv        . (A^2)^i . B_bar
//   K[2i+1] = (Cv.A_bar). (A^2)^i . B_bar
// (drops the A^4 matmul: 4 matmuls total). Writes K transposed: Kout[k*128+d].
__global__ __launch_bounds__(256) void s4_discretize(
    const float* __restrict__ Ag,   // (128,64,64)
    const float* __restrict__ Bg,   // (128,64)
    const float* __restrict__ Cg,   // (128,64)
    float* __restrict__ Kout)       // (32,128)
{
  __shared__ float Ms[64 * PAD];    // M -> A_bar
  __shared__ float Xs[64 * PAD];    // seed -> M^-1
  __shared__ float Ts[64 * PAD];    // (2I - MX0) -> A^2
  __shared__ float U16[16][PAD];    // (A^2)^i . B_bar rows
  __shared__ float Pr[4][64];
  __shared__ float Bv[64], Cv0[64], Bb[64], Cc1[64];

  const int d   = blockIdx.x;
  const int tid = threadIdx.x;
  const int i0  = (tid >> 4) << 3;  // mm: 8-row tile (t<128)
  const int j0  = (tid & 15) << 2;  // mm: 4-col tile
  const int q   = tid >> 6;         // wave id 0..3
  const int ln  = tid & 63;
  const int co  = tid >> 2;         // chain: output row 0..63
  const int cc  = tid & 3;          // chain: 16-elem chunk

  // ---- P1: load, build M = I - 0.05A ----
  for (int idx = tid; idx < 4096; idx += 256) {
    int i = idx >> 6, j = idx & 63;
    float a = Ag[(size_t)d * 4096 + idx];
    Ms[i * PAD + j] = ((i == j) ? 1.f : 0.f) - 0.05f * a;
  }
  if (tid < 64) { Bv[tid] = Bg[d * 64 + tid]; Cv0[tid] = Cg[d * 64 + tid]; }
  __syncthreads();

  float acc[32];

  // ---- P2: acc = M^2 (in regs); seed X0 = C2*M^2 + C1*M + C0*I -> Xs ----
  if (tid < 128) {
    mm_acc8x4(Ms, Ms, i0, j0, acc);
    #pragma unroll
    for (int m = 0; m < 8; ++m) {
      f4 mo = *(const f4*)&Ms[(i0 + m) * PAD + j0];
      f4 t;
      #pragma unroll
      for (int c = 0; c < 4; ++c)
        t[c] = SEED_C2 * acc[m*4+c] + SEED_C1 * mo[c]
             + ((i0 + m == j0 + c) ? SEED_C0 : 0.f);
      *(f4*)&Xs[(i0 + m) * PAD + j0] = t;
    }
  }
  __syncthreads();

  // ---- P3: Ts = 2I - M*X0 ----
  if (tid < 128) {
    mm_acc8x4(Ms, Xs, i0, j0, acc);
    #pragma unroll
    for (int m = 0; m < 8; ++m) {
      f4 t;
      #pragma unroll
      for (int c = 0; c < 4; ++c)
        t[c] = ((i0 + m == j0 + c) ? 2.f : 0.f) - acc[m*4+c];
      *(f4*)&Ts[(i0 + m) * PAD + j0] = t;
    }
  }
  __syncthreads();

  // ---- P4: X1 = X0*(2I - M X0)  (Newton; resid ~2.5e-5) ----
  if (tid < 128) mm_acc8x4(Xs, Ts, i0, j0, acc);
  __syncthreads();                  // all reads of X0 done
  if (tid < 128) {
    #pragma unroll
    for (int m = 0; m < 8; ++m) {
      f4 t = {acc[m*4+0], acc[m*4+1], acc[m*4+2], acc[m*4+3]};
      *(f4*)&Xs[(i0 + m) * PAD + j0] = t;
    }
  }
  __syncthreads();                  // Xs = M^-1

  // ---- P5: B_bar = 0.1 * X Bv ; A_bar = 2X - I -> Ms ----
  {
    float p = 0.f;
    #pragma unroll
    for (int m = 0; m < 16; ++m) p += Xs[ln * PAD + q * 16 + m] * Bv[q * 16 + m];
    Pr[q][ln] = p;
  }
  for (int idx = tid; idx < 4096; idx += 256) {
    int i = idx >> 6, j = idx & 63;
    Ms[i * PAD + j] = 2.f * Xs[i * PAD + j] - ((i == j) ? 1.f : 0.f);
  }
  __syncthreads();
  if (tid < 64) Bb[tid] = 0.1f * (Pr[0][tid] + Pr[1][tid] + Pr[2][tid] + Pr[3][tid]);
  __syncthreads();

  // ---- P6: c1 = Cv . A_bar (column matvec) ; P7: Ts = A_bar^2 ; u_0 = B_bar ----
  {
    float p = 0.f;
    #pragma unroll
    for (int m = 0; m < 16; ++m)
      p += Cv0[cc * 16 + m] * Ms[(cc * 16 + m) * PAD + co];
    p += __shfl_xor(p, 1);
    p += __shfl_xor(p, 2);
    if (cc == 0) Cc1[co] = p;
  }
  if (tid < 128) {
    mm_acc8x4(Ms, Ms, i0, j0, acc);
    #pragma unroll
    for (int m = 0; m < 8; ++m) {
      f4 t = {acc[m*4+0], acc[m*4+1], acc[m*4+2], acc[m*4+3]};
      *(f4*)&Ts[(i0 + m) * PAD + j0] = t;   // Ts dead since P4 -> safe
    }
  }
  if (tid < 64) U16[0][tid] = Bb[tid];
  __syncthreads();

  // ---- P8: u_i = A^2 . u_{i-1}, i=1..15 (f4 reads, shfl reduce, 1 barrier) ----
  for (int i = 1; i < 16; ++i) {
    const float* Arow = &Ts[co * PAD + cc * 16];
    const float* uv   = &U16[i - 1][cc * 16];
    float p = 0.f;
    #pragma unroll
    for (int j = 0; j < 4; ++j) {
      f4 a = *(const f4*)&Arow[4 * j];
      f4 u = *(const f4*)&uv[4 * j];
      p += a[0]*u[0] + a[1]*u[1] + a[2]*u[2] + a[3]*u[3];
    }
    p += __shfl_xor(p, 1);
    p += __shfl_xor(p, 2);
    if (cc == 0) U16[i][co] = p;
    __syncthreads();
  }

  // ---- P9: K[k] = c_{k&1} . u_{k>>1}, write transposed ----
  {
    const int k = tid >> 3, e = tid & 7;
    const float* cvec = (k & 1) ? Cc1 : Cv0;
    const float* uvec = U16[k >> 1];
    float p = 0.f;
    #pragma unroll
    for (int j = 0; j < 8; ++j) p += cvec[e * 8 + j] * uvec[e * 8 + j];
    p += __shfl_xor(p, 1);
    p += __shfl_xor(p, 2);
    p += __shfl_xor(p, 4);
    if (e == 0) Kout[k * 128 + d] = p;
  }
}

// Depthwise causal conv, 32 taps. Block: 32 d x 256 t tile; thread = (dl, g) does 32 t.
// LDS 40,832 B <= 40,960 -> 4 blocks/CU (16 waves); grid 1024 = exactly one
// full-residency round (no tail). Halo ratio 287/256 = 1.12x.
__global__ __launch_bounds__(256, 4) void s4_conv(
    const float* __restrict__ xg,   // (16,4096,128)
    const float* __restrict__ Ktg,  // (32,128) transposed K
    float* __restrict__ yg)         // (16,4096,128)
{
  __shared__ float xs[287 * 32];    // 36,736 B
  __shared__ float Ks[32 * 32];     //  4,096 B

  const int tid = threadIdx.y * 32 + threadIdx.x;
  const int tc  = blockIdx.x;
  const int dq  = blockIdx.y;
  const int b   = blockIdx.z;
  const int d0  = dq * 32;
  const int t0  = tc * 256;

  for (int idx = tid; idx < 1024; idx += 256)
    Ks[idx] = Ktg[(idx >> 5) * 128 + d0 + (idx & 31)];

  const float* xb = xg + (size_t)b * 4096 * 128 + d0;
  for (int idx = tid; idx < 287 * 8; idx += 256) {
    int row = idx >> 3, c4 = (idx & 7) << 2;
    int t = t0 - 31 + row;
    f4 v = {0.f, 0.f, 0.f, 0.f};
    if (t >= 0) v = *(const f4*)&xb[(size_t)t * 128 + c4];
    *(f4*)&xs[row * 32 + c4] = v;
  }
  __syncthreads();

  const int dl = threadIdx.x;
  const int g  = threadIdx.y;

  float acc[32];
  #pragma unroll
  for (int t = 0; t < 32; ++t) acc[t] = 0.f;

  float w[47];
  #pragma unroll
  for (int k0 = 0; k0 < 32; k0 += 16) {
    const int base = g * 32 + 16 - k0;
    #pragma unroll
    for (int jj = 0; jj < 47; ++jj) w[jj] = xs[(base + jj) * 32 + dl];
    #pragma unroll
    for (int k = k0; k < k0 + 16; ++k) {
      float kv = Ks[k * 32 + dl];
      #pragma unroll
      for (int t = 0; t < 32; ++t)
        acc[t] += kv * w[t + (k0 + 15 - k)];
    }
  }

  float* yb = yg + ((size_t)b * 4096 + t0 + g * 32) * 128 + d0 + dl;
  #pragma unroll
  for (int t = 0; t < 32; ++t)
    yb[(size_t)t * 128] = acc[t];
}

extern "C" void kernel_launch(void* const* d_in, const int* in_sizes, int n_in,
                              void* d_out, int out_size, void* d_ws, size_t ws_size,
                              hipStream_t stream) {
  const float* x = (const float*)d_in[0];
  const float* A = (const float*)d_in[1];
  const float* B = (const float*)d_in[2];
  const float* C = (const float*)d_in[3];
  float* y  = (float*)d_out;
  float* Kt = (float*)d_ws;   // 32*128*4 = 16 KB scratch

  s4_discretize<<<128, 256, 0, stream>>>(A, B, C, Kt);
  dim3 grid(16, 4, 16), block(32, 8);
  s4_conv<<<grid, block, 0, stream>>>(x, Kt, y);
}

// Round 3
// 111.218 us; speedup vs baseline: 1.0344x; 1.0344x over previous
//
#include <hip/hip_runtime.h>

typedef float f4 __attribute__((ext_vector_type(4)));

#define PAD 68   // 64x64 LDS matrix row stride: 272 B, 16B-aligned

// Chebyshev deg-2 minimax seed for 1/lambda on [2.55, 4.40]:
// X0 = C2*M^2 + C1*M + C0*I ; residual ~5.0e-3, after 1 Newton ~2.5e-5
#define SEED_C2 0.0251681f
#define SEED_C1 (-0.262380f)
#define SEED_C0 0.895613f

// 4x4 tile, 256 threads cover 64x64. Rows 4 apart (272 % 128B = free 2-way),
// proven conflict-free in R1. acc[m*4+c] = sum_n L[i0+m][n] * R[n][j0+c].
__device__ __forceinline__ void mm_acc(const float* L, const float* R,
                                       int i0, int j0, float acc[16]) {
  #pragma unroll
  for (int m = 0; m < 16; ++m) acc[m] = 0.f;
  #pragma unroll
  for (int n = 0; n < 64; n += 4) {
    f4 La[4], Rb[4];
    #pragma unroll
    for (int m = 0; m < 4; ++m) La[m] = *(const f4*)&L[(i0 + m) * PAD + n];
    #pragma unroll
    for (int p = 0; p < 4; ++p) Rb[p] = *(const f4*)&R[(n + p) * PAD + j0];
    #pragma unroll
    for (int m = 0; m < 4; ++m)
      #pragma unroll
      for (int p = 0; p < 4; ++p)
        #pragma unroll
        for (int c = 0; c < 4; ++c)
          acc[m * 4 + c] += La[m][p] * Rb[p][c];
  }
}

// One block per channel d. K[k] = Cv . A_bar^k . B_bar, k=0..31, via
// Cheb-seeded Newton inverse + power doubling (A^2, A^4).
// K[k] = (Cv.A_bar^(k&3)) . (A^4)^(k>>2) . B_bar. Writes K transposed.
__global__ __launch_bounds__(256) void s4_discretize(
    const float* __restrict__ Ag,   // (128,64,64)
    const float* __restrict__ Bg,   // (128,64)
    const float* __restrict__ Cg,   // (128,64)
    float* __restrict__ Kout)       // (32,128)
{
  __shared__ float Ms[64 * PAD];    // M -> A_bar
  __shared__ float Xs[64 * PAD];    // X0 -> M^-1 -> A_bar^4
  __shared__ float Ts[64 * PAD];    // (2I - M X0) -> A_bar^2
  __shared__ float C4[4][PAD];      // Cv . A_bar^j   (f4-aligned rows)
  __shared__ float U8[8][72];       // (A^4)^i . B_bar (f4-aligned rows)
  __shared__ float Bv[64], Cv0[64], Bb[64];

  const int d   = blockIdx.x;
  const int tid = threadIdx.x;
  const int i0  = (tid >> 4) << 2;  // mm: 4-row tile
  const int j0  = (tid & 15) << 2;  // mm: 4-col tile
  const int co  = tid >> 2;         // chains: output index 0..63
  const int cc  = tid & 3;          // chains: 16-elem chunk (adjacent lanes)

  // ---- P1: load, build M = I - 0.05A (f4) ----
  {
    const f4* Af = (const f4*)(Ag + (size_t)d * 4096);
    for (int v = tid; v < 1024; v += 256) {
      int i = v >> 4, jc = (v & 15) << 2;
      f4 a = Af[v];
      f4 t;
      #pragma unroll
      for (int c = 0; c < 4; ++c)
        t[c] = ((i == jc + c) ? 1.f : 0.f) - 0.05f * a[c];
      *(f4*)&Ms[i * PAD + jc] = t;
    }
  }
  if (tid < 64) { Bv[tid] = Bg[d * 64 + tid]; Cv0[tid] = Cg[d * 64 + tid]; }
  __syncthreads();

  float acc[16];

  // ---- P2: acc = M^2 ; fused seed X0 = C2*M^2 + C1*M + C0*I -> Xs ----
  mm_acc(Ms, Ms, i0, j0, acc);
  #pragma unroll
  for (int m = 0; m < 4; ++m) {
    f4 mo = *(const f4*)&Ms[(i0 + m) * PAD + j0];
    f4 t;
    #pragma unroll
    for (int c = 0; c < 4; ++c)
      t[c] = SEED_C2 * acc[m*4+c] + SEED_C1 * mo[c]
           + ((i0 + m == j0 + c) ? SEED_C0 : 0.f);
    *(f4*)&Xs[(i0 + m) * PAD + j0] = t;
  }
  __syncthreads();

  // ---- P3: Ts = 2I - M*X0 (fused epilogue) ----
  mm_acc(Ms, Xs, i0, j0, acc);
  #pragma unroll
  for (int m = 0; m < 4; ++m) {
    f4 t;
    #pragma unroll
    for (int c = 0; c < 4; ++c)
      t[c] = ((i0 + m == j0 + c) ? 2.f : 0.f) - acc[m*4+c];
    *(f4*)&Ts[(i0 + m) * PAD + j0] = t;
  }
  __syncthreads();

  // ---- P4: X1 = X0*(2I - M X0)  (Newton; resid ~2.5e-5) ----
  mm_acc(Xs, Ts, i0, j0, acc);
  __syncthreads();                  // all reads of X0 done
  #pragma unroll
  for (int m = 0; m < 4; ++m) {
    f4 t = {acc[m*4+0], acc[m*4+1], acc[m*4+2], acc[m*4+3]};
    *(f4*)&Xs[(i0 + m) * PAD + j0] = t;
  }
  __syncthreads();                  // Xs = M^-1

  // ---- P5: B_bar = 0.1*X Bv (adjacent-lane partials); A_bar = 2X-I -> Ms ----
  {
    float p = 0.f;
    #pragma unroll
    for (int j = 0; j < 4; ++j) {
      f4 x = *(const f4*)&Xs[co * PAD + cc * 16 + 4 * j];
      f4 b = *(const f4*)&Bv[cc * 16 + 4 * j];
      p += x[0]*b[0] + x[1]*b[1] + x[2]*b[2] + x[3]*b[3];
    }
    p += __shfl_xor(p, 1);
    p += __shfl_xor(p, 2);
    if (cc == 0) Bb[co] = 0.1f * p;
  }
  for (int v = tid; v < 1024; v += 256) {
    int i = v >> 4, jc = (v & 15) << 2;
    f4 x = *(const f4*)&Xs[i * PAD + jc];
    f4 t;
    #pragma unroll
    for (int c = 0; c < 4; ++c)
      t[c] = 2.f * x[c] - ((i == jc + c) ? 1.f : 0.f);
    *(f4*)&Ms[i * PAD + jc] = t;
  }
  if (tid < 64) C4[0][tid] = Cv0[tid];
  __syncthreads();

  // ---- P6: C-chain c_j = c_{j-1}.A_bar, j=1..3 (1 barrier/step) ----
  for (int j = 1; j < 4; ++j) {
    float p = 0.f;
    #pragma unroll
    for (int m = 0; m < 16; ++m)
      p += C4[j - 1][cc * 16 + m] * Ms[(cc * 16 + m) * PAD + co];
    p += __shfl_xor(p, 1);
    p += __shfl_xor(p, 2);
    if (cc == 0) C4[j][co] = p;
    __syncthreads();
  }

  // ---- P7: Ts = A_bar^2 ----
  mm_acc(Ms, Ms, i0, j0, acc);
  #pragma unroll
  for (int m = 0; m < 4; ++m) {
    f4 t = {acc[m*4+0], acc[m*4+1], acc[m*4+2], acc[m*4+3]};
    *(f4*)&Ts[(i0 + m) * PAD + j0] = t;   // Ts dead since P4 -> safe
  }
  __syncthreads();

  // ---- P8: Xs = A_bar^4 ; u_0 = B_bar ----
  mm_acc(Ts, Ts, i0, j0, acc);
  #pragma unroll
  for (int m = 0; m < 4; ++m) {
    f4 t = {acc[m*4+0], acc[m*4+1], acc[m*4+2], acc[m*4+3]};
    *(f4*)&Xs[(i0 + m) * PAD + j0] = t;   // Xs dead since P5 -> safe
  }
  if (tid < 64) U8[0][tid] = Bb[tid];
  __syncthreads();

  // ---- P9: U-chain u_i = A^4 . u_{i-1}, i=1..7 (f4 reads, 1 barrier/step) ----
  for (int i = 1; i < 8; ++i) {
    float p = 0.f;
    #pragma unroll
    for (int j = 0; j < 4; ++j) {
      f4 a = *(const f4*)&Xs[co * PAD + cc * 16 + 4 * j];
      f4 u = *(const f4*)&U8[i - 1][cc * 16 + 4 * j];
      p += a[0]*u[0] + a[1]*u[1] + a[2]*u[2] + a[3]*u[3];
    }
    p += __shfl_xor(p, 1);
    p += __shfl_xor(p, 2);
    if (cc == 0) U8[i][co] = p;
    __syncthreads();
  }

  // ---- P10: K[k] = c_{k&3} . u_{k>>2}, write transposed ----
  {
    const int k = tid >> 3, e = tid & 7;
    const float* cvec = C4[k & 3];
    const float* uvec = U8[k >> 2];
    f4 c0 = *(const f4*)&cvec[e * 8];
    f4 c1 = *(const f4*)&cvec[e * 8 + 4];
    f4 u0 = *(const f4*)&uvec[e * 8];
    f4 u1 = *(const f4*)&uvec[e * 8 + 4];
    float p = c0[0]*u0[0] + c0[1]*u0[1] + c0[2]*u0[2] + c0[3]*u0[3]
            + c1[0]*u1[0] + c1[1]*u1[1] + c1[2]*u1[2] + c1[3]*u1[3];
    p += __shfl_xor(p, 1);
    p += __shfl_xor(p, 2);
    p += __shfl_xor(p, 4);
    if (e == 0) Kout[k * 128 + d] = p;
  }
}

// Depthwise causal conv, 32 taps. Block: 32 d x 256 t tile; thread = (dl, g) does 32 t.
// LDS 40,832 B <= 40,960 -> 4 blocks/CU (16 waves); grid 1024 = exactly one
// full-residency round (no tail). Halo ratio 287/256 = 1.12x. ~HBM floor.
__global__ __launch_bounds__(256, 4) void s4_conv(
    const float* __restrict__ xg,   // (16,4096,128)
    const float* __restrict__ Ktg,  // (32,128) transposed K
    float* __restrict__ yg)         // (16,4096,128)
{
  __shared__ float xs[287 * 32];    // 36,736 B
  __shared__ float Ks[32 * 32];     //  4,096 B

  const int tid = threadIdx.y * 32 + threadIdx.x;
  const int tc  = blockIdx.x;
  const int dq  = blockIdx.y;
  const int b   = blockIdx.z;
  const int d0  = dq * 32;
  const int t0  = tc * 256;

  for (int idx = tid; idx < 1024; idx += 256)
    Ks[idx] = Ktg[(idx >> 5) * 128 + d0 + (idx & 31)];

  const float* xb = xg + (size_t)b * 4096 * 128 + d0;
  for (int idx = tid; idx < 287 * 8; idx += 256) {
    int row = idx >> 3, c4 = (idx & 7) << 2;
    int t = t0 - 31 + row;
    f4 v = {0.f, 0.f, 0.f, 0.f};
    if (t >= 0) v = *(const f4*)&xb[(size_t)t * 128 + c4];
    *(f4*)&xs[row * 32 + c4] = v;
  }
  __syncthreads();

  const int dl = threadIdx.x;
  const int g  = threadIdx.y;

  float acc[32];
  #pragma unroll
  for (int t = 0; t < 32; ++t) acc[t] = 0.f;

  float w[47];
  #pragma unroll
  for (int k0 = 0; k0 < 32; k0 += 16) {
    const int base = g * 32 + 16 - k0;
    #pragma unroll
    for (int jj = 0; jj < 47; ++jj) w[jj] = xs[(base + jj) * 32 + dl];
    #pragma unroll
    for (int k = k0; k < k0 + 16; ++k) {
      float kv = Ks[k * 32 + dl];
      #pragma unroll
      for (int t = 0; t < 32; ++t)
        acc[t] += kv * w[t + (k0 + 15 - k)];
    }
  }

  float* yb = yg + ((size_t)b * 4096 + t0 + g * 32) * 128 + d0 + dl;
  #pragma unroll
  for (int t = 0; t < 32; ++t)
    yb[(size_t)t * 128] = acc[t];
}

extern "C" void kernel_launch(void* const* d_in, const int* in_sizes, int n_in,
                              void* d_out, int out_size, void* d_ws, size_t ws_size,
                              hipStream_t stream) {
  const float* x = (const float*)d_in[0];
  const float* A = (const float*)d_in[1];
  const float* B = (const float*)d_in[2];
  const float* C = (const float*)d_in[3];
  float* y  = (float*)d_out;
  float* Kt = (float*)d_ws;   // 32*128*4 = 16 KB scratch

  s4_discretize<<<128, 256, 0, stream>>>(A, B, C, Kt);
  dim3 grid(16, 4, 16), block(32, 8);
  s4_conv<<<grid, block, 0, stream>>>(x, Kt, y);
}

// Round 4
// 110.258 us; speedup vs baseline: 1.0434x; 1.0087x over previous
//
#include <hip/hip_runtime.h>

typedef float f4 __attribute__((ext_vector_type(4)));

#define PAD 68   // 64x64 LDS matrix row stride: 272 B, 16B-aligned

// Chebyshev deg-2 minimax seed for 1/lambda on [2.55, 4.40]:
// X0 = C2*M^2 + C1*M + C0*I ; residual ~5.0e-3, after 1 Newton ~2.5e-5
#define SEED_C2 0.0251681f
#define SEED_C1 (-0.262380f)
#define SEED_C0 0.895613f

// 4x4 tile, 256 threads cover 64x64. Rows 4 apart (272 B ≡ 16 mod 32 banks ->
// free 2-way), proven conflict-free. acc[m*4+c] = sum_n L[i0+m][n]*R[n][j0+c].
__device__ __forceinline__ void mm_acc(const float* L, const float* R,
                                       int i0, int j0, float acc[16]) {
  #pragma unroll
  for (int m = 0; m < 16; ++m) acc[m] = 0.f;
  #pragma unroll
  for (int n = 0; n < 64; n += 4) {
    f4 La[4], Rb[4];
    #pragma unroll
    for (int m = 0; m < 4; ++m) La[m] = *(const f4*)&L[(i0 + m) * PAD + n];
    #pragma unroll
    for (int p = 0; p < 4; ++p) Rb[p] = *(const f4*)&R[(n + p) * PAD + j0];
    #pragma unroll
    for (int m = 0; m < 4; ++m)
      #pragma unroll
      for (int p = 0; p < 4; ++p)
        #pragma unroll
        for (int c = 0; c < 4; ++c)
          acc[m * 4 + c] += La[m][p] * Rb[p][c];
  }
}

// Two blocks per channel d (grid 256 = all CUs). Both halves compute the
// Cheb-seeded Newton inverse (3 mm) + A_bar^2 (1 mm) redundantly; then
//   K[k] = (Cv . A_bar^(k&1)) . (A_bar^2)^(k>>1) . B_bar
//   half 0: u-chain i=0..7  -> K[0..15]
//   half 1: u-chain i=0..15 -> K[16..31]
// Critical path: 4 mm + 16 reg-hoisted matvec steps (vs 5 mm + 10 before).
// Writes K transposed: Kout[k*128 + d].
__global__ __launch_bounds__(256) void s4_discretize(
    const float* __restrict__ Ag,   // (128,64,64)
    const float* __restrict__ Bg,   // (128,64)
    const float* __restrict__ Cg,   // (128,64)
    float* __restrict__ Kout)       // (32,128)
{
  __shared__ float Ms[64 * PAD];    // M -> A_bar
  __shared__ float Xs[64 * PAD];    // X0 -> M^-1
  __shared__ float Ts[64 * PAD];    // (2I - M X0) -> A_bar^2
  __shared__ float U16[16][72];     // (A^2)^i . B_bar (f4-aligned rows)
  __shared__ float Bv[64], Cv0[64], Bb[64], Cc1[64];

  const int d    = blockIdx.x >> 1;
  const int half = blockIdx.x & 1;
  const int tid  = threadIdx.x;
  const int i0   = (tid >> 4) << 2;  // mm: 4-row tile
  const int j0   = (tid & 15) << 2;  // mm: 4-col tile
  const int co   = tid >> 2;         // chains: output index 0..63
  const int cc   = tid & 3;          // chains: 16-elem chunk (adjacent lanes)

  // ---- P1: load, build M = I - 0.05A (f4) ----
  {
    const f4* Af = (const f4*)(Ag + (size_t)d * 4096);
    for (int v = tid; v < 1024; v += 256) {
      int i = v >> 4, jc = (v & 15) << 2;
      f4 a = Af[v];
      f4 t;
      #pragma unroll
      for (int c = 0; c < 4; ++c)
        t[c] = ((i == jc + c) ? 1.f : 0.f) - 0.05f * a[c];
      *(f4*)&Ms[i * PAD + jc] = t;
    }
  }
  if (tid < 64) { Bv[tid] = Bg[d * 64 + tid]; Cv0[tid] = Cg[d * 64 + tid]; }
  __syncthreads();

  float acc[16];

  // ---- P2: acc = M^2 ; fused seed X0 = C2*M^2 + C1*M + C0*I -> Xs ----
  mm_acc(Ms, Ms, i0, j0, acc);
  #pragma unroll
  for (int m = 0; m < 4; ++m) {
    f4 mo = *(const f4*)&Ms[(i0 + m) * PAD + j0];
    f4 t;
    #pragma unroll
    for (int c = 0; c < 4; ++c)
      t[c] = SEED_C2 * acc[m*4+c] + SEED_C1 * mo[c]
           + ((i0 + m == j0 + c) ? SEED_C0 : 0.f);
    *(f4*)&Xs[(i0 + m) * PAD + j0] = t;
  }
  __syncthreads();

  // ---- P3: Ts = 2I - M*X0 (fused epilogue) ----
  mm_acc(Ms, Xs, i0, j0, acc);
  #pragma unroll
  for (int m = 0; m < 4; ++m) {
    f4 t;
    #pragma unroll
    for (int c = 0; c < 4; ++c)
      t[c] = ((i0 + m == j0 + c) ? 2.f : 0.f) - acc[m*4+c];
    *(f4*)&Ts[(i0 + m) * PAD + j0] = t;
  }
  __syncthreads();

  // ---- P4: X1 = X0*(2I - M X0)  (Newton; resid ~2.5e-5) ----
  mm_acc(Xs, Ts, i0, j0, acc);
  __syncthreads();                  // all reads of X0 done
  #pragma unroll
  for (int m = 0; m < 4; ++m) {
    f4 t = {acc[m*4+0], acc[m*4+1], acc[m*4+2], acc[m*4+3]};
    *(f4*)&Xs[(i0 + m) * PAD + j0] = t;
  }
  __syncthreads();                  // Xs = M^-1

  // ---- P5: B_bar = 0.1*X Bv (adjacent-lane partials); A_bar = 2X-I -> Ms ----
  {
    float p = 0.f;
    #pragma unroll
    for (int j = 0; j < 4; ++j) {
      f4 x = *(const f4*)&Xs[co * PAD + cc * 16 + 4 * j];
      f4 b = *(const f4*)&Bv[cc * 16 + 4 * j];
      p += x[0]*b[0] + x[1]*b[1] + x[2]*b[2] + x[3]*b[3];
    }
    p += __shfl_xor(p, 1);
    p += __shfl_xor(p, 2);
    if (cc == 0) Bb[co] = 0.1f * p;
  }
  for (int v = tid; v < 1024; v += 256) {
    int i = v >> 4, jc = (v & 15) << 2;
    f4 x = *(const f4*)&Xs[i * PAD + jc];
    f4 t;
    #pragma unroll
    for (int c = 0; c < 4; ++c)
      t[c] = 2.f * x[c] - ((i == jc + c) ? 1.f : 0.f);
    *(f4*)&Ms[i * PAD + jc] = t;
  }
  __syncthreads();                  // Ms = A_bar, Bb = B_bar

  // ---- P6: Ts = A_bar^2 ; c1 = Cv . A_bar ; u_0 = B_bar ----
  mm_acc(Ms, Ms, i0, j0, acc);
  #pragma unroll
  for (int m = 0; m < 4; ++m) {
    f4 t = {acc[m*4+0], acc[m*4+1], acc[m*4+2], acc[m*4+3]};
    *(f4*)&Ts[(i0 + m) * PAD + j0] = t;   // Ts dead since P4 -> safe
  }
  {
    float p = 0.f;
    #pragma unroll
    for (int m = 0; m < 16; ++m)
      p += Cv0[cc * 16 + m] * Ms[(cc * 16 + m) * PAD + co];
    p += __shfl_xor(p, 1);
    p += __shfl_xor(p, 2);
    if (cc == 0) Cc1[co] = p;
  }
  if (tid < 64) U16[0][tid] = Bb[tid];
  __syncthreads();

  // ---- P7: hoist this thread's A^2 slice into registers (fixed all steps) ----
  f4 areg[4];
  #pragma unroll
  for (int j = 0; j < 4; ++j)
    areg[j] = *(const f4*)&Ts[co * PAD + cc * 16 + 4 * j];

  // ---- P8: u_i = A^2 . u_{i-1}; half0: i<=7, half1: i<=15 ----
  const int NS = half ? 15 : 7;
  for (int i = 1; i <= NS; ++i) {
    float p = 0.f;
    #pragma unroll
    for (int j = 0; j < 4; ++j) {
      f4 u = *(const f4*)&U16[i - 1][cc * 16 + 4 * j];
      p += areg[j][0]*u[0] + areg[j][1]*u[1] + areg[j][2]*u[2] + areg[j][3]*u[3];
    }
    p += __shfl_xor(p, 1);
    p += __shfl_xor(p, 2);
    if (cc == 0) U16[i][co] = p;
    __syncthreads();
  }

  // ---- P9: K[k] = c_{k&1} . u_{k>>1}, k = half*16 + (tid>>4) ----
  {
    const int kl = tid >> 4, e = tid & 15;
    const int k  = half * 16 + kl;
    const float* cvec = (k & 1) ? Cc1 : Cv0;
    const float* uvec = U16[k >> 1];
    f4 c = *(const f4*)&cvec[e * 4];
    f4 u = *(const f4*)&uvec[e * 4];
    float p = c[0]*u[0] + c[1]*u[1] + c[2]*u[2] + c[3]*u[3];
    p += __shfl_xor(p, 1);
    p += __shfl_xor(p, 2);
    p += __shfl_xor(p, 4);
    p += __shfl_xor(p, 8);
    if (e == 0) Kout[k * 128 + d] = p;
  }
}

// Depthwise causal conv, 32 taps. Block: 32 d x 256 t tile; thread = (dl, g) does 32 t.
// LDS 40,832 B <= 40,960 -> 4 blocks/CU (16 waves); grid 1024 = exactly one
// full-residency round (no tail). Halo ratio 287/256 = 1.12x. ~HBM floor.
__global__ __launch_bounds__(256, 4) void s4_conv(
    const float* __restrict__ xg,   // (16,4096,128)
    const float* __restrict__ Ktg,  // (32,128) transposed K
    float* __restrict__ yg)         // (16,4096,128)
{
  __shared__ float xs[287 * 32];    // 36,736 B
  __shared__ float Ks[32 * 32];     //  4,096 B

  const int tid = threadIdx.y * 32 + threadIdx.x;
  const int tc  = blockIdx.x;
  const int dq  = blockIdx.y;
  const int b   = blockIdx.z;
  const int d0  = dq * 32;
  const int t0  = tc * 256;

  for (int idx = tid; idx < 1024; idx += 256)
    Ks[idx] = Ktg[(idx >> 5) * 128 + d0 + (idx & 31)];

  const float* xb = xg + (size_t)b * 4096 * 128 + d0;
  for (int idx = tid; idx < 287 * 8; idx += 256) {
    int row = idx >> 3, c4 = (idx & 7) << 2;
    int t = t0 - 31 + row;
    f4 v = {0.f, 0.f, 0.f, 0.f};
    if (t >= 0) v = *(const f4*)&xb[(size_t)t * 128 + c4];
    *(f4*)&xs[row * 32 + c4] = v;
  }
  __syncthreads();

  const int dl = threadIdx.x;
  const int g  = threadIdx.y;

  float acc[32];
  #pragma unroll
  for (int t = 0; t < 32; ++t) acc[t] = 0.f;

  float w[47];
  #pragma unroll
  for (int k0 = 0; k0 < 32; k0 += 16) {
    const int base = g * 32 + 16 - k0;
    #pragma unroll
    for (int jj = 0; jj < 47; ++jj) w[jj] = xs[(base + jj) * 32 + dl];
    #pragma unroll
    for (int k = k0; k < k0 + 16; ++k) {
      float kv = Ks[k * 32 + dl];
      #pragma unroll
      for (int t = 0; t < 32; ++t)
        acc[t] += kv * w[t + (k0 + 15 - k)];
    }
  }

  float* yb = yg + ((size_t)b * 4096 + t0 + g * 32) * 128 + d0 + dl;
  #pragma unroll
  for (int t = 0; t < 32; ++t)
    yb[(size_t)t * 128] = acc[t];
}

extern "C" void kernel_launch(void* const* d_in, const int* in_sizes, int n_in,
                              void* d_out, int out_size, void* d_ws, size_t ws_size,
                              hipStream_t stream) {
  const float* x = (const float*)d_in[0];
  const float* A = (const float*)d_in[1];
  const float* B = (const float*)d_in[2];
  const float* C = (const float*)d_in[3];
  float* y  = (float*)d_out;
  float* Kt = (float*)d_ws;   // 32*128*4 = 16 KB scratch

  s4_discretize<<<256, 256, 0, stream>>>(A, B, C, Kt);
  dim3 grid(16, 4, 16), block(32, 8);
  s4_conv<<<grid, block, 0, stream>>>(x, Kt, y);
}